// Round 5
// baseline (317.887 us; speedup 1.0000x reference)
//
#include <hip/hip_runtime.h>

// Unfold: x[B=32, C=64, H=64, W=64] fp32, KH=KW=3, stride=1
// out[b][c*9 + i*3 + j][ho*62 + wo] = x[b][c][ho+i][wo+j]; out [32, 576, 3844].
//
// One block per (b,c) channel, 16 KB LDS staging (swizzled). Emission is
// restructured so each WAVE writes a single linear output stream (like the
// 6.1 TB/s fill kernel): thread t walks float4 indices f = t, t+256, ... over
// the block's contiguous 9*3844-float region in k-major order. 3844 = 4*961,
// so a float4 never straddles a k-row. Stores are nontemporal (no L2 alloc
// for 283 MB of streaming writes) via a native clang vector type (HIP float4
// is a class and __builtin_nontemporal_store rejects it). LDS reads are
// lane-stride-4 -> swizzle p -> p + (p>>5) keeps them bank-conflict-free.

#define B 32
#define C 64
#define H 64
#define W 64
#define HO 62
#define WO 62
#define L (HO * WO)        // 3844
#define L4 (L / 4)         // 961
#define KK 9
#define F_TOT (KK * L4)    // 8649 float4 per (b,c)

typedef float f32x4 __attribute__((ext_vector_type(4)));

__device__ __forceinline__ int sw(int p) { return p + (p >> 5); }

__global__ __launch_bounds__(256, 8) void unfold_kernel(
    const float* __restrict__ x, float* __restrict__ out) {
    __shared__ float tile[H * W + (H * W) / 32];  // swizzled, 16.5 KB

    const int c   = blockIdx.x;   // 0..63
    const int b   = blockIdx.y;   // 0..31
    const int tid = threadIdx.x;  // 0..255

    // ---- Stage channel (b,c): 1024 float4 loads, swizzled LDS writes. ----
    const f32x4* __restrict__ src =
        (const f32x4*)(x + (((size_t)(b * C + c)) << 12));
#pragma unroll
    for (int r = 0; r < 4; ++r) {
        const int p4 = tid + r * 256;
        f32x4 v = src[p4];
        const int p = p4 * 4;
        tile[sw(p)]     = v.x;  // stride-4 across lanes: conflict-free swizzled
        tile[sw(p + 1)] = v.y;
        tile[sw(p + 2)] = v.z;
        tile[sw(p + 3)] = v.w;
    }
    __syncthreads();

    // ---- Emit: each wave streams one contiguous run of the 138 KB region. ----
    f32x4* __restrict__ dst4 = (f32x4*)out + (size_t)(b * C + c) * F_TOT;

    for (int f = tid; f < F_TOT; f += 256) {
        const int k  = f / L4;          // 0..8   (magic-mul div)
        const int r  = f - k * L4;      // 0..960
        const int i  = k / 3;           // 0..2
        const int j  = k - i * 3;       // 0..2
        const int l0 = r * 4;
        int ho = l0 / WO;               // magic-mul div
        int wo = l0 - ho * WO;
        int addr = (ho + i) * W + wo + j;

        float v[4];
#pragma unroll
        for (int q = 0; q < 4; ++q) {
            v[q] = tile[sw(addr)];
            ++addr;
            ++wo;
            if (wo == WO) { wo = 0; addr += (W - WO); }
        }
        f32x4 o;
        o.x = v[0]; o.y = v[1]; o.z = v[2]; o.w = v[3];
        __builtin_nontemporal_store(o, &dst4[f]);  // global_store_dwordx4 nt
    }
}

extern "C" void kernel_launch(void* const* d_in, const int* in_sizes, int n_in,
                              void* d_out, int out_size, void* d_ws, size_t ws_size,
                              hipStream_t stream) {
    const float* x = (const float*)d_in[0];
    float* out = (float*)d_out;

    dim3 block(256, 1, 1);
    dim3 grid(C, B, 1);  // 2048 blocks = 8/CU resident (16.5 KB LDS, low VGPR)
    unfold_kernel<<<grid, block, 0, stream>>>(x, out);
}